// Round 3
// baseline (113.714 us; speedup 1.0000x reference)
//
#include <hip/hip_runtime.h>
#include <math.h>

#define HMAP 1024
#define WMAP 1024

__device__ __forceinline__ int clampi(int x, int hi) {
    return x < 0 ? 0 : (x > hi ? hi : x);
}

// Single dispatch, single block of 1024 threads = 16 waves. Wave w handles
// points {w, w+16, ...} (8 points each for n=128). Per point: cooperative
// 33x33 patch scan (17 independent loads/lane, one latency round, overlapped
// across the 16 co-resident waves), 6-step shuffle min-reduce. Chebyshev
// guard keeps it exact: any map pixel outside the patch has d2 >= 17^2=289,
// so if both mins <= 289 they are the global mins (P(fallback) ~ 0.7^1089).
// Full-map cooperative fallback preserves unconditional exactness. Final
// mean: per-point losses to LDS, first wave shuffle-sums, one global store.
// No workspace, no atomics, no memset node.
__global__ __launch_bounds__(1024)
void roadloss_all(const float* __restrict__ hd_map,
                  const int* __restrict__ pred,
                  int n,
                  float* __restrict__ out) {
    __shared__ float lossbuf[128];
    const int tid  = threadIdx.x;
    const int wave = tid >> 6;
    const int lane = tid & 63;

    if (tid < 128) lossbuf[tid] = 0.0f;
    __syncthreads();

    for (int pt = wave; pt < n; pt += 16) {
        const int px = pred[2 * pt];      // row-center (pred[:,0] vs rows)
        const int py = pred[2 * pt + 1];  // col-center (pred[:,1] vs cols)

        // 2x2 neighbor check — the reference SWAPS coords here (rows from
        // pred[:,1], cols from pred[:,0]) and JAX clamps OOB indices.
        const int r0c = clampi(py - 1, HMAP - 1), r1c = clampi(py, HMAP - 1);
        const int c0c = clampi(px - 1, WMAP - 1), c1c = clampi(px, WMAP - 1);
        const float n00 = hd_map[r0c * WMAP + c0c];
        const float n01 = hd_map[r0c * WMAP + c1c];
        const float n10 = hd_map[r1c * WMAP + c0c];
        const float n11 = hd_map[r1c * WMAP + c1c];

        float best_on = 1e30f, best_off = 1e30f;

        const int R = 16;
#pragma unroll
        for (int ii = 0; ii < 18; ++ii) {
            int i = lane + ii * 64;
            if (i < 33 * 33) {
                int dr = i / 33 - R;
                int dc = i % 33 - R;
                int r = px + dr, c = py + dc;
                if ((unsigned)r < (unsigned)HMAP && (unsigned)c < (unsigned)WMAP) {
                    float v  = hd_map[r * WMAP + c];
                    float d2 = (float)(dr * dr + dc * dc);  // exact in fp32
                    if (v != 0.0f) best_on  = fminf(best_on,  d2);
                    else           best_off = fminf(best_off, d2);
                }
            }
        }
#pragma unroll
        for (int s = 1; s < 64; s <<= 1) {
            best_on  = fminf(best_on,  __shfl_xor(best_on,  s, 64));
            best_off = fminf(best_off, __shfl_xor(best_off, s, 64));
        }

        // Exact full-map fallback (statistically never taken at 30% density).
        const float guard = (float)((R + 1) * (R + 1));  // 289
        if (!(best_on <= guard && best_off <= guard)) {
            for (int i = lane; i < HMAP * WMAP; i += 64) {
                int r = i >> 10, c = i & (WMAP - 1);
                int dri = r - px, dci = c - py;
                float d2 = (float)(dri * dri + dci * dci);  // < 2^24, exact
                float v = hd_map[i];
                if (v != 0.0f) best_on  = fminf(best_on,  d2);
                else           best_off = fminf(best_off, d2);
            }
#pragma unroll
            for (int s = 1; s < 64; s <<= 1) {
                best_on  = fminf(best_on,  __shfl_xor(best_on,  s, 64));
                best_off = fminf(best_off, __shfl_xor(best_off, s, 64));
            }
        }

        if (lane == 0 && pt < 128) {
            bool outside_frame = (px < 0) | (px > HMAP) | (py < 0) | (py > WMAP);
            bool outside_road  = (n00 == 1.0f) | (n01 == 1.0f) |
                                 (n10 == 1.0f) | (n11 == 1.0f);
            const float K1 = 21.7f, K2 = 40.0f;
            const float LN2 = 0.6931471805599453f;
            lossbuf[pt] = outside_frame
                              ? 0.0f
                              : (outside_road
                                     ? expf(sqrtf(best_off) * (LN2 / K2))
                                     : expf(-best_on / K1));
        }
    }

    __syncthreads();
    if (tid < 64) {
        float s = lossbuf[tid] + lossbuf[tid + 64];
#pragma unroll
        for (int d = 1; d < 64; d <<= 1)
            s += __shfl_xor(s, d, 64);
        if (tid == 0) out[0] = s / (float)n;
    }
}

extern "C" void kernel_launch(void* const* d_in, const int* in_sizes, int n_in,
                              void* d_out, int out_size, void* d_ws, size_t ws_size,
                              hipStream_t stream) {
    const float* hd_map = (const float*)d_in[0];
    const int*   pred   = (const int*)d_in[1];
    float* out = (float*)d_out;
    int n = in_sizes[1] / 2;  // 128
    roadloss_all<<<1, 1024, 0, stream>>>(hd_map, pred, n, out);
}

// Round 4
// 86.145 us; speedup vs baseline: 1.3200x; 1.3200x over previous
//
#include <hip/hip_runtime.h>
#include <hip/hip_cooperative_groups.h>
#include <math.h>

namespace cg = cooperative_groups;

#define HMAP 1024
#define WMAP 1024

__device__ __forceinline__ int clampi(int x, int hi) {
    return x < 0 ? 0 : (x > hi ? hi : x);
}

// Cooperative launch: 128 blocks x 64 threads, one wave per point, one
// graph node, no workspace init, no atomics.
//  - Patch scan: radius-16 (33x33 = 1089 px). All 17 loads per lane use
//    CLAMPED addresses (always in-bounds) and are hoisted into registers
//    first, so the compiler issues them all before waiting -> ONE HBM
//    latency round (~900 cyc) per point, parallel across 128 CUs.
//  - Chebyshev guard: any pixel outside the patch has d2 >= 17^2 = 289,
//    so patch mins <= 289 are the exact global mins. Full-map cooperative
//    fallback (P ~ 0.7^1089) keeps the kernel unconditionally exact.
//  - grid.sync(), then block 0 sums ws[0..n) and writes the mean.
__global__ __launch_bounds__(64)
void roadloss_coop(const float* __restrict__ hd_map,
                   const int* __restrict__ pred,
                   int n,
                   float* __restrict__ out,
                   float* __restrict__ ws) {
    const int pt   = blockIdx.x;
    const int lane = threadIdx.x;

    if (pt < n) {
        const int px = pred[2 * pt];      // row-center (pred[:,0] vs rows)
        const int py = pred[2 * pt + 1];  // col-center (pred[:,1] vs cols)

        // 2x2 neighbor check — reference SWAPS coords (rows from pred[:,1],
        // cols from pred[:,0]); JAX clamps OOB indices.
        const int r0c = clampi(py - 1, HMAP - 1), r1c = clampi(py, HMAP - 1);
        const int c0c = clampi(px - 1, WMAP - 1), c1c = clampi(px, WMAP - 1);
        const float n00 = hd_map[r0c * WMAP + c0c];
        const float n01 = hd_map[r0c * WMAP + c1c];
        const float n10 = hd_map[r1c * WMAP + c0c];
        const float n11 = hd_map[r1c * WMAP + c1c];

        const int R = 16;

        // ---- Stage 1: issue all patch loads (clamped, unconditional) ----
        float v[18];
#pragma unroll
        for (int ii = 0; ii < 18; ++ii) {
            int i  = lane + ii * 64;
            int dr = i / 33 - R;
            int dc = i % 33 - R;
            int r  = clampi(px + dr, HMAP - 1);
            int c  = clampi(py + dc, WMAP - 1);
            v[ii]  = hd_map[r * WMAP + c];
        }

        // ---- Stage 2: process (two accumulator pairs to cut dep chain) ----
        float on0 = 1e30f, off0 = 1e30f, on1 = 1e30f, off1 = 1e30f;
#pragma unroll
        for (int ii = 0; ii < 18; ++ii) {
            int i  = lane + ii * 64;
            int dr = i / 33 - R;
            int dc = i % 33 - R;
            bool inb = (i < 33 * 33) &&
                       ((unsigned)(px + dr) < (unsigned)HMAP) &&
                       ((unsigned)(py + dc) < (unsigned)WMAP);
            float d2 = (float)(dr * dr + dc * dc);  // exact in fp32
            if (inb) {
                if (ii & 1) {
                    if (v[ii] != 0.0f) on1  = fminf(on1,  d2);
                    else               off1 = fminf(off1, d2);
                } else {
                    if (v[ii] != 0.0f) on0  = fminf(on0,  d2);
                    else               off0 = fminf(off0, d2);
                }
            }
        }
        float best_on  = fminf(on0,  on1);
        float best_off = fminf(off0, off1);

#pragma unroll
        for (int s = 1; s < 64; s <<= 1) {
            best_on  = fminf(best_on,  __shfl_xor(best_on,  s, 64));
            best_off = fminf(best_off, __shfl_xor(best_off, s, 64));
        }

        // Exact full-map fallback (statistically never taken @30% density).
        const float guard = (float)((R + 1) * (R + 1));  // 289
        if (!(best_on <= guard && best_off <= guard)) {
            for (int i = lane; i < HMAP * WMAP; i += 64) {
                int r = i >> 10, c = i & (WMAP - 1);
                int dri = r - px, dci = c - py;
                float d2 = (float)(dri * dri + dci * dci);  // < 2^24, exact
                float m = hd_map[i];
                if (m != 0.0f) best_on  = fminf(best_on,  d2);
                else           best_off = fminf(best_off, d2);
            }
#pragma unroll
            for (int s = 1; s < 64; s <<= 1) {
                best_on  = fminf(best_on,  __shfl_xor(best_on,  s, 64));
                best_off = fminf(best_off, __shfl_xor(best_off, s, 64));
            }
        }

        if (lane == 0) {
            bool outside_frame = (px < 0) | (px > HMAP) | (py < 0) | (py > WMAP);
            bool outside_road  = (n00 == 1.0f) | (n01 == 1.0f) |
                                 (n10 == 1.0f) | (n11 == 1.0f);
            const float K1 = 21.7f, K2 = 40.0f;
            const float LN2 = 0.6931471805599453f;
            ws[pt] = outside_frame
                         ? 0.0f
                         : (outside_road ? expf(sqrtf(best_off) * (LN2 / K2))
                                         : expf(-best_on / K1));
        }
    }

    cg::this_grid().sync();

    if (blockIdx.x == 0) {
        float s = 0.0f;
        for (int i = lane; i < n; i += 64) s += ws[i];
#pragma unroll
        for (int d = 1; d < 64; d <<= 1) s += __shfl_xor(s, d, 64);
        if (lane == 0) out[0] = s / (float)n;
    }
}

extern "C" void kernel_launch(void* const* d_in, const int* in_sizes, int n_in,
                              void* d_out, int out_size, void* d_ws, size_t ws_size,
                              hipStream_t stream) {
    const float* hd_map = (const float*)d_in[0];
    const int*   pred   = (const int*)d_in[1];
    float* out = (float*)d_out;
    float* ws  = (float*)d_ws;
    int n = in_sizes[1] / 2;  // 128

    void* args[] = {(void*)&hd_map, (void*)&pred, (void*)&n,
                    (void*)&out, (void*)&ws};
    hipLaunchCooperativeKernel((const void*)roadloss_coop,
                               dim3((unsigned)n), dim3(64), args, 0, stream);
}

// Round 5
// 58.523 us; speedup vs baseline: 1.9431x; 1.4720x over previous
//
#include <hip/hip_runtime.h>
#include <math.h>

#define HMAP 1024
#define WMAP 1024

__device__ __forceinline__ int clampi(int x, int hi) {
    return x < 0 ? 0 : (x > hi ? hi : x);
}

// Kernel 1: 128 blocks x 64 threads, one wave per point. Radius-16 patch
// (33x33 = 1089 px): all 17 loads/lane use CLAMPED (always in-bounds)
// addresses hoisted into registers -> one HBM latency round per point,
// parallel across 128 CUs. Chebyshev guard (any pixel outside the patch has
// d2 >= 17^2 = 289) certifies exactness; cooperative full-map fallback
// (P ~ 0.7^1089) keeps it unconditionally exact. Per-point loss stored to
// ws[pt] with a plain store — no init, no atomics.
__global__ __launch_bounds__(64)
void roadloss_points(const float* __restrict__ hd_map,
                     const int* __restrict__ pred,
                     int n,
                     float* __restrict__ ws) {
    const int pt   = blockIdx.x;
    const int lane = threadIdx.x;
    if (pt >= n) return;

    const int px = pred[2 * pt];      // row-center (pred[:,0] vs rows)
    const int py = pred[2 * pt + 1];  // col-center (pred[:,1] vs cols)

    // 2x2 neighbor check — reference SWAPS coords (rows from pred[:,1],
    // cols from pred[:,0]); JAX clamps OOB indices.
    const int r0c = clampi(py - 1, HMAP - 1), r1c = clampi(py, HMAP - 1);
    const int c0c = clampi(px - 1, WMAP - 1), c1c = clampi(px, WMAP - 1);
    const float n00 = hd_map[r0c * WMAP + c0c];
    const float n01 = hd_map[r0c * WMAP + c1c];
    const float n10 = hd_map[r1c * WMAP + c0c];
    const float n11 = hd_map[r1c * WMAP + c1c];

    const int R = 16;

    // Stage 1: issue all patch loads (clamped => unconditional).
    float v[18];
#pragma unroll
    for (int ii = 0; ii < 18; ++ii) {
        int i  = lane + ii * 64;
        int dr = i / 33 - R;
        int dc = i % 33 - R;
        int r  = clampi(px + dr, HMAP - 1);
        int c  = clampi(py + dc, WMAP - 1);
        v[ii]  = hd_map[r * WMAP + c];
    }

    // Stage 2: process with split accumulators.
    float on0 = 1e30f, off0 = 1e30f, on1 = 1e30f, off1 = 1e30f;
#pragma unroll
    for (int ii = 0; ii < 18; ++ii) {
        int i  = lane + ii * 64;
        int dr = i / 33 - R;
        int dc = i % 33 - R;
        bool inb = (i < 33 * 33) &&
                   ((unsigned)(px + dr) < (unsigned)HMAP) &&
                   ((unsigned)(py + dc) < (unsigned)WMAP);
        float d2 = (float)(dr * dr + dc * dc);  // exact in fp32
        if (inb) {
            if (ii & 1) {
                if (v[ii] != 0.0f) on1  = fminf(on1,  d2);
                else               off1 = fminf(off1, d2);
            } else {
                if (v[ii] != 0.0f) on0  = fminf(on0,  d2);
                else               off0 = fminf(off0, d2);
            }
        }
    }
    float best_on  = fminf(on0,  on1);
    float best_off = fminf(off0, off1);

#pragma unroll
    for (int s = 1; s < 64; s <<= 1) {
        best_on  = fminf(best_on,  __shfl_xor(best_on,  s, 64));
        best_off = fminf(best_off, __shfl_xor(best_off, s, 64));
    }

    // Exact full-map fallback (statistically never taken @30% density).
    const float guard = (float)((R + 1) * (R + 1));  // 289
    if (!(best_on <= guard && best_off <= guard)) {
        for (int i = lane; i < HMAP * WMAP; i += 64) {
            int r = i >> 10, c = i & (WMAP - 1);
            int dri = r - px, dci = c - py;
            float d2 = (float)(dri * dri + dci * dci);  // < 2^24, exact
            float m = hd_map[i];
            if (m != 0.0f) best_on  = fminf(best_on,  d2);
            else           best_off = fminf(best_off, d2);
        }
#pragma unroll
        for (int s = 1; s < 64; s <<= 1) {
            best_on  = fminf(best_on,  __shfl_xor(best_on,  s, 64));
            best_off = fminf(best_off, __shfl_xor(best_off, s, 64));
        }
    }

    if (lane == 0) {
        bool outside_frame = (px < 0) | (px > HMAP) | (py < 0) | (py > WMAP);
        bool outside_road  = (n00 == 1.0f) | (n01 == 1.0f) |
                             (n10 == 1.0f) | (n11 == 1.0f);
        const float K1 = 21.7f, K2 = 40.0f;
        const float LN2 = 0.6931471805599453f;
        ws[pt] = outside_frame
                     ? 0.0f
                     : (outside_road ? expf(sqrtf(best_off) * (LN2 / K2))
                                     : expf(-best_on / K1));
    }
}

// Kernel 2: one wave sums the n per-point losses and writes the mean.
__global__ __launch_bounds__(64)
void roadloss_reduce(const float* __restrict__ ws, int n,
                     float* __restrict__ out) {
    const int lane = threadIdx.x;
    float s = 0.0f;
    for (int i = lane; i < n; i += 64) s += ws[i];
#pragma unroll
    for (int d = 1; d < 64; d <<= 1) s += __shfl_xor(s, d, 64);
    if (lane == 0) out[0] = s / (float)n;
}

extern "C" void kernel_launch(void* const* d_in, const int* in_sizes, int n_in,
                              void* d_out, int out_size, void* d_ws, size_t ws_size,
                              hipStream_t stream) {
    const float* hd_map = (const float*)d_in[0];
    const int*   pred   = (const int*)d_in[1];
    float* out = (float*)d_out;
    float* ws  = (float*)d_ws;
    int n = in_sizes[1] / 2;  // 128

    roadloss_points<<<n, 64, 0, stream>>>(hd_map, pred, n, ws);
    roadloss_reduce<<<1, 64, 0, stream>>>(ws, n, out);
}